// Round 1
// baseline (2865.521 us; speedup 1.0000x reference)
//
#include <hip/hip_runtime.h>

// Problem constants (from reference setup_inputs)
static constexpr int B = 4, C = 3, H = 1080, W = 1920;
static constexpr int HW = H * W;          // 2,073,600
static constexpr int NPIX = B * HW;       // 8,294,400
static constexpr int BLOCK = 256;

// Depth key must match numpy bit-exactly: no FMA contraction, round-half-even.
__device__ __forceinline__ int depth_key(float fx, float fy) {
    float m2 = __fadd_rn(__fmul_rn(fx, fx), __fmul_rn(fy, fy));
    return (int)rintf(__fmul_rn(sqrtf(m2), 1000.0f));
}

// Pass 1: scatter-max quantized motion magnitude into the depth buffer.
__global__ __launch_bounds__(BLOCK) void k_depth(const float2* __restrict__ flow,
                                                 int* __restrict__ dbuf) {
    int i = blockIdx.x * BLOCK + threadIdx.x;
    if (i >= NPIX) return;
    int b   = i / HW;
    int pix = i - b * HW;
    int h   = pix / W;
    int w   = pix - h * W;

    float2 f = flow[i];
    float x = (float)w + f.x;
    float y = (float)h + f.y;
    int x0 = (int)floorf(x);
    int y0 = (int)floorf(y);
    int d  = depth_key(f.x, f.y);
    int base = b * HW;

    #pragma unroll
    for (int cy = 0; cy < 2; ++cy) {
        int ty = y0 + cy;
        if (ty < 0 || ty >= H) continue;
        #pragma unroll
        for (int cx = 0; cx < 2; ++cx) {
            int tx = x0 + cx;
            if (tx < 0 || tx >= W) continue;
            atomicMax(&dbuf[base + ty * W + tx], d);
        }
    }
}

// Pass 2: accumulate depth-test winners (weights + 3 channels) into wght / out.
__global__ __launch_bounds__(BLOCK) void k_splat(const float* __restrict__ im0,
                                                 const float2* __restrict__ flow,
                                                 const int* __restrict__ dbuf,
                                                 float* __restrict__ wght,
                                                 float* __restrict__ out) {
    int i = blockIdx.x * BLOCK + threadIdx.x;
    if (i >= NPIX) return;
    int b   = i / HW;
    int pix = i - b * HW;
    int h   = pix / W;
    int w   = pix - h * W;

    float2 f = flow[i];
    float x = (float)w + f.x;
    float y = (float)h + f.y;
    float x0f = floorf(x), y0f = floorf(y);
    int x0 = (int)x0f, y0 = (int)y0f;
    float ax = __fsub_rn(x, x0f);
    float ay = __fsub_rn(y, y0f);
    int d = depth_key(f.x, f.y);

    const float* src = im0 + (size_t)b * C * HW + pix;
    float c0 = src[0];
    float c1 = src[HW];
    float c2 = src[2 * HW];

    int base = b * HW;
    float wx[2] = { __fsub_rn(1.0f, ax), ax };
    float wy[2] = { __fsub_rn(1.0f, ay), ay };

    #pragma unroll
    for (int cy = 0; cy < 2; ++cy) {
        int ty = y0 + cy;
        if (ty < 0 || ty >= H) continue;
        #pragma unroll
        for (int cx = 0; cx < 2; ++cx) {
            int tx = x0 + cx;
            if (tx < 0 || tx >= W) continue;
            int idx = base + ty * W + tx;
            if (d != dbuf[idx]) continue;
            float wgt = __fmul_rn(wx[cx], wy[cy]);
            atomicAdd(&wght[idx], wgt);
            float* o = out + (size_t)b * C * HW + ty * W + tx;
            atomicAdd(&o[0],      __fmul_rn(c0, wgt));
            atomicAdd(&o[HW],     __fmul_rn(c1, wgt));
            atomicAdd(&o[2 * HW], __fmul_rn(c2, wgt));
        }
    }
}

// Pass 3: in-place normalize out[b,c,:,:] /= max(wght[b,:,:], eps).
__global__ __launch_bounds__(BLOCK) void k_norm(float* __restrict__ out,
                                                const float* __restrict__ wght) {
    int i = blockIdx.x * BLOCK + threadIdx.x;
    if (i >= NPIX) return;
    int b   = i / HW;
    int pix = i - b * HW;
    float wv = fmaxf(wght[i], 1e-5f);
    float* o = out + (size_t)b * C * HW + pix;
    o[0]      = __fdiv_rn(o[0], wv);
    o[HW]     = __fdiv_rn(o[HW], wv);
    o[2 * HW] = __fdiv_rn(o[2 * HW], wv);
}

extern "C" void kernel_launch(void* const* d_in, const int* in_sizes, int n_in,
                              void* d_out, int out_size, void* d_ws, size_t ws_size,
                              hipStream_t stream) {
    const float*  im0  = (const float*)d_in[0];   // [B,C,H,W]
    const float2* flow = (const float2*)d_in[1];  // [B,H,W,2] as float2
    float* out = (float*)d_out;                   // [B,C,H,W]

    int*   dbuf = (int*)d_ws;                     // NPIX int32
    float* wght = (float*)((char*)d_ws + (size_t)NPIX * sizeof(int)); // NPIX f32

    // Zero accumulators (harness poisons d_out/d_ws with 0xAA before each call).
    hipMemsetAsync(d_out, 0, (size_t)out_size * sizeof(float), stream);
    hipMemsetAsync(d_ws, 0, (size_t)NPIX * (sizeof(int) + sizeof(float)), stream);

    int grid = (NPIX + BLOCK - 1) / BLOCK;
    k_depth<<<grid, BLOCK, 0, stream>>>(flow, dbuf);
    k_splat<<<grid, BLOCK, 0, stream>>>(im0, flow, dbuf, wght, out);
    k_norm <<<grid, BLOCK, 0, stream>>>(out, wght);
}

// Round 2
// 1478.751 us; speedup vs baseline: 1.9378x; 1.9378x over previous
//
#include <hip/hip_runtime.h>

// Problem constants (from reference setup_inputs)
static constexpr int B = 4, C = 3, H = 1080, W = 1920;
static constexpr int HW = H * W;          // 2,073,600
static constexpr int NPIX = B * HW;       // 8,294,400
static constexpr int BLOCK = 256;

// Tiling of the TARGET domain. A workgroup owns one 64x64 target tile and
// scans sources in the tile +/- MARGIN window. Sources with
// max(|fx|,|fy|) <= FMAX are provably contained: corner-to-source offset
// <= floor(62)+1 = 63 <= MARGIN-1, so every corner landing in tile T has its
// source inside T's window. Larger flows (~0.4% for sigma=20) take the
// global-atomic fallback path.
static constexpr int TILE = 64;
static constexpr int MARGIN = 64;
static constexpr int WIN = TILE + 2 * MARGIN;   // 192
static constexpr float FMAX = 62.0f;
static constexpr int TX = (W + TILE - 1) / TILE;  // 30
static constexpr int TY = (H + TILE - 1) / TILE;  // 17

// Depth key must match numpy bit-exactly: no FMA contraction, round-half-even.
// (Identical to the round-1 passing kernel — winner selection is an exact
// integer compare, so this must be byte-for-byte the same everywhere.)
__device__ __forceinline__ int depth_key(float fx, float fy) {
    float m2 = __fadd_rn(__fmul_rn(fx, fx), __fmul_rn(fy, fy));
    return (int)rintf(__fmul_rn(sqrtf(m2), 1000.0f));
}

// ---------------------------------------------------------------------------
// Pass 1a: tiled depth max. LDS atomicMax, then PLAIN coalesced store of the
// whole tile (tiles partition the image -> every dbuf entry written; fallback
// atomicMax runs in a later kernel, ordered by the stream).
__global__ __launch_bounds__(BLOCK) void k_depth_tiled(const float2* __restrict__ flow,
                                                       int* __restrict__ dbuf) {
    __shared__ int dmax[TILE * TILE];
    const int tid = threadIdx.x;
    for (int i = tid; i < TILE * TILE; i += BLOCK) dmax[i] = 0;
    __syncthreads();

    const int b = blockIdx.z;
    const int tx0 = blockIdx.x * TILE;
    const int ty0 = blockIdx.y * TILE;
    const float2* fb = flow + (size_t)b * HW;

    for (int idx = tid; idx < WIN * WIN; idx += BLOCK) {
        int wy = idx / WIN, wx = idx - wy * WIN;
        int gy = ty0 - MARGIN + wy;
        int gx = tx0 - MARGIN + wx;
        if (gx < 0 || gx >= W || gy < 0 || gy >= H) continue;
        float2 f = fb[gy * W + gx];
        if (!(fabsf(f.x) <= FMAX && fabsf(f.y) <= FMAX)) continue;  // fallback path
        float x = (float)gx + f.x;
        float y = (float)gy + f.y;
        int x0 = (int)floorf(x);
        int y0 = (int)floorf(y);
        int d = depth_key(f.x, f.y);
        #pragma unroll
        for (int cy = 0; cy < 2; ++cy) {
            int ty = y0 + cy;
            if (ty < ty0 || ty >= ty0 + TILE || ty >= H) continue;
            #pragma unroll
            for (int cx = 0; cx < 2; ++cx) {
                int tx = x0 + cx;
                if (tx < tx0 || tx >= tx0 + TILE || tx >= W) continue;
                atomicMax(&dmax[(ty - ty0) * TILE + (tx - tx0)], d);
            }
        }
    }
    __syncthreads();

    int* db = dbuf + (size_t)b * HW;
    for (int i = tid; i < TILE * TILE; i += BLOCK) {
        int ly = i / TILE, lx = i - ly * TILE;
        int gy = ty0 + ly, gx = tx0 + lx;
        if (gy < H && gx < W) db[gy * W + gx] = dmax[i];
    }
}

// Pass 1b: large-flow fallback depth (global atomicMax; ~0.4% of sources).
__global__ __launch_bounds__(BLOCK) void k_depth_fb(const float2* __restrict__ flow,
                                                    int* __restrict__ dbuf) {
    int i = blockIdx.x * BLOCK + threadIdx.x;
    if (i >= NPIX) return;
    float2 f = flow[i];
    if (fabsf(f.x) <= FMAX && fabsf(f.y) <= FMAX) return;
    int b = i / HW;
    int pix = i - b * HW;
    int h = pix / W;
    int w = pix - h * W;
    float x = (float)w + f.x;
    float y = (float)h + f.y;
    int x0 = (int)floorf(x);
    int y0 = (int)floorf(y);
    int d = depth_key(f.x, f.y);
    int base = b * HW;
    #pragma unroll
    for (int cy = 0; cy < 2; ++cy) {
        int ty = y0 + cy;
        if (ty < 0 || ty >= H) continue;
        #pragma unroll
        for (int cx = 0; cx < 2; ++cx) {
            int tx = x0 + cx;
            if (tx < 0 || tx >= W) continue;
            atomicMax(&dbuf[base + ty * W + tx], d);
        }
    }
}

// ---------------------------------------------------------------------------
// Pass 2a: tiled accumulation. Depth test reads dbuf directly (the 16 KB tile
// stays hot in L1/L2); winners accumulate into LDS SoA acc[4][TILE*TILE]
// (w, c0, c1, c2). Plain coalesced store of out + wght (fallback adds later).
__global__ __launch_bounds__(BLOCK) void k_accum_tiled(const float* __restrict__ im0,
                                                       const float2* __restrict__ flow,
                                                       const int* __restrict__ dbuf,
                                                       float* __restrict__ wght,
                                                       float* __restrict__ out) {
    __shared__ float acc[4][TILE * TILE];   // 64 KB
    const int tid = threadIdx.x;
    for (int i = tid; i < TILE * TILE; i += BLOCK) {
        acc[0][i] = 0.0f; acc[1][i] = 0.0f; acc[2][i] = 0.0f; acc[3][i] = 0.0f;
    }
    __syncthreads();

    const int b = blockIdx.z;
    const int tx0 = blockIdx.x * TILE;
    const int ty0 = blockIdx.y * TILE;
    const float2* fb = flow + (size_t)b * HW;
    const float* ib = im0 + (size_t)b * C * HW;
    const int* db = dbuf + (size_t)b * HW;

    for (int idx = tid; idx < WIN * WIN; idx += BLOCK) {
        int wy = idx / WIN, wx = idx - wy * WIN;
        int gy = ty0 - MARGIN + wy;
        int gx = tx0 - MARGIN + wx;
        if (gx < 0 || gx >= W || gy < 0 || gy >= H) continue;
        float2 f = fb[gy * W + gx];
        if (!(fabsf(f.x) <= FMAX && fabsf(f.y) <= FMAX)) continue;  // fallback path
        float x = (float)gx + f.x;
        float y = (float)gy + f.y;
        float x0f = floorf(x), y0f = floorf(y);
        int x0 = (int)x0f, y0 = (int)y0f;
        float ax = __fsub_rn(x, x0f);
        float ay = __fsub_rn(y, y0f);
        int d = depth_key(f.x, f.y);
        float wxv[2] = { __fsub_rn(1.0f, ax), ax };
        float wyv[2] = { __fsub_rn(1.0f, ay), ay };

        int   lpix[4];
        float lw[4];
        int nwin = 0;
        #pragma unroll
        for (int cy = 0; cy < 2; ++cy) {
            int ty = y0 + cy;
            if (ty < ty0 || ty >= ty0 + TILE || ty >= H) continue;
            #pragma unroll
            for (int cx = 0; cx < 2; ++cx) {
                int tx = x0 + cx;
                if (tx < tx0 || tx >= tx0 + TILE || tx >= W) continue;
                int gidx = ty * W + tx;
                if (d != db[gidx]) continue;
                lpix[nwin] = (ty - ty0) * TILE + (tx - tx0);
                lw[nwin] = __fmul_rn(wxv[cx], wyv[cy]);
                ++nwin;
            }
        }
        if (nwin) {
            int spix = gy * W + gx;
            float c0 = ib[spix];
            float c1 = ib[spix + HW];
            float c2 = ib[spix + 2 * HW];
            for (int k = 0; k < nwin; ++k) {
                int p = lpix[k];
                float wgt = lw[k];
                atomicAdd(&acc[0][p], wgt);
                atomicAdd(&acc[1][p], __fmul_rn(c0, wgt));
                atomicAdd(&acc[2][p], __fmul_rn(c1, wgt));
                atomicAdd(&acc[3][p], __fmul_rn(c2, wgt));
            }
        }
    }
    __syncthreads();

    float* wb = wght + (size_t)b * HW;
    float* ob = out + (size_t)b * C * HW;
    for (int i = tid; i < TILE * TILE; i += BLOCK) {
        int ly = i / TILE, lx = i - ly * TILE;
        int gy = ty0 + ly, gx = tx0 + lx;
        if (gy >= H || gx >= W) continue;
        int gidx = gy * W + gx;
        wb[gidx]          = acc[0][i];
        ob[gidx]          = acc[1][i];
        ob[gidx + HW]     = acc[2][i];
        ob[gidx + 2 * HW] = acc[3][i];
    }
}

// Pass 2b: large-flow fallback accumulation (global atomicAdd on top).
__global__ __launch_bounds__(BLOCK) void k_accum_fb(const float* __restrict__ im0,
                                                    const float2* __restrict__ flow,
                                                    const int* __restrict__ dbuf,
                                                    float* __restrict__ wght,
                                                    float* __restrict__ out) {
    int i = blockIdx.x * BLOCK + threadIdx.x;
    if (i >= NPIX) return;
    float2 f = flow[i];
    if (fabsf(f.x) <= FMAX && fabsf(f.y) <= FMAX) return;
    int b = i / HW;
    int pix = i - b * HW;
    int h = pix / W;
    int w = pix - h * W;
    float x = (float)w + f.x;
    float y = (float)h + f.y;
    float x0f = floorf(x), y0f = floorf(y);
    int x0 = (int)x0f, y0 = (int)y0f;
    float ax = __fsub_rn(x, x0f);
    float ay = __fsub_rn(y, y0f);
    int d = depth_key(f.x, f.y);
    const float* src = im0 + (size_t)b * C * HW + pix;
    float c0 = src[0];
    float c1 = src[HW];
    float c2 = src[2 * HW];
    int base = b * HW;
    float wxv[2] = { __fsub_rn(1.0f, ax), ax };
    float wyv[2] = { __fsub_rn(1.0f, ay), ay };
    #pragma unroll
    for (int cy = 0; cy < 2; ++cy) {
        int ty = y0 + cy;
        if (ty < 0 || ty >= H) continue;
        #pragma unroll
        for (int cx = 0; cx < 2; ++cx) {
            int tx = x0 + cx;
            if (tx < 0 || tx >= W) continue;
            int idx = base + ty * W + tx;
            if (d != dbuf[idx]) continue;
            float wgt = __fmul_rn(wxv[cx], wyv[cy]);
            atomicAdd(&wght[idx], wgt);
            float* o = out + (size_t)b * C * HW + ty * W + tx;
            atomicAdd(&o[0],      __fmul_rn(c0, wgt));
            atomicAdd(&o[HW],     __fmul_rn(c1, wgt));
            atomicAdd(&o[2 * HW], __fmul_rn(c2, wgt));
        }
    }
}

// Pass 3: in-place normalize out[b,c,:,:] /= max(wght[b,:,:], eps).
__global__ __launch_bounds__(BLOCK) void k_norm(float* __restrict__ out,
                                                const float* __restrict__ wght) {
    int i = blockIdx.x * BLOCK + threadIdx.x;
    if (i >= NPIX) return;
    int b = i / HW;
    int pix = i - b * HW;
    float wv = fmaxf(wght[i], 1e-5f);
    float* o = out + (size_t)b * C * HW + pix;
    o[0]      = __fdiv_rn(o[0], wv);
    o[HW]     = __fdiv_rn(o[HW], wv);
    o[2 * HW] = __fdiv_rn(o[2 * HW], wv);
}

extern "C" void kernel_launch(void* const* d_in, const int* in_sizes, int n_in,
                              void* d_out, int out_size, void* d_ws, size_t ws_size,
                              hipStream_t stream) {
    const float*  im0  = (const float*)d_in[0];   // [B,C,H,W]
    const float2* flow = (const float2*)d_in[1];  // [B,H,W,2] as float2
    float* out = (float*)d_out;                   // [B,C,H,W]

    int*   dbuf = (int*)d_ws;                                          // NPIX int32
    float* wght = (float*)((char*)d_ws + (size_t)NPIX * sizeof(int));  // NPIX f32

    dim3 tgrid(TX, TY, B);
    int lgrid = (NPIX + BLOCK - 1) / BLOCK;

    // Tiles partition the image and plain-store every pixel of dbuf/wght/out,
    // so no memsets are needed; fallback kernels atomically merge afterwards.
    k_depth_tiled<<<tgrid, BLOCK, 0, stream>>>(flow, dbuf);
    k_depth_fb   <<<lgrid, BLOCK, 0, stream>>>(flow, dbuf);
    k_accum_tiled<<<tgrid, BLOCK, 0, stream>>>(im0, flow, dbuf, wght, out);
    k_accum_fb   <<<lgrid, BLOCK, 0, stream>>>(im0, flow, dbuf, wght, out);
    k_norm       <<<lgrid, BLOCK, 0, stream>>>(out, wght);
}